// Round 5
// baseline (258.158 us; speedup 1.0000x reference)
//
#include <hip/hip_runtime.h>
#include <hip/hip_bf16.h>

// PatchConv2d: out[b,o,h,w] = conv3x3(x,kernel) + 0.1*(h+w)*patch_sum[b,h,w] + bias[o]
// x:(16,64,128,128) f32, kernel:(128,64,3,3) f32, bias:(128,) f32 -> out(16,128,128,128) f32
//
// R8: rolling-row fused kernel. Block = 4-row h-strip (grid 32x16, 2/CU).
//     3-slot rolling LDS row buffer: steady state stages ONE new row per
//     output row (1.5x total vs R7's 3x), prefetched into registers at step
//     start (T14) so HBM latency hides under the MFMA phase. Barriers are raw
//     s_barrier + lgkmcnt(0) only (m201 pattern) -- NO vmcnt drain, so
//     prefetch loads and epilogue stores stay in flight across barriers.
//     Rolling 3-slot column sums (Srow) -> pre-summed ps3 for the epilogue.

typedef __attribute__((ext_vector_type(8))) short short8;
typedef __attribute__((ext_vector_type(4))) float f32x4;

#define B_COEF 0.1f
constexpr int CI = 64, CO = 128, H = 128, W = 128;
constexpr int SH = 4;     // output rows per block
constexpr int XPAD = 72;  // fallback-path LDS stride

static __device__ inline short bf16s(float v) {
    __hip_bfloat16 b = __float2bfloat16(v);
    return *reinterpret_cast<short*>(&b);
}

// barrier that does NOT drain vmcnt: ds-writes flushed, loads/stores fly on
static __device__ inline void bar_lgkm() {
    asm volatile("s_waitcnt lgkmcnt(0)" ::: "memory");
    __builtin_amdgcn_s_barrier();
    asm volatile("" ::: "memory");
}
static __device__ inline void bar_plain() {
    asm volatile("" ::: "memory");
    __builtin_amdgcn_s_barrier();
    asm volatile("" ::: "memory");
}

// ============================ fast path ====================================

// kernel f32 [oc][ci][3][3] -> bf16 wq[tap][kc][oc][32] (ci = kc*32+j)
__global__ void prep_wq(const float* __restrict__ wgt, __hip_bfloat16* __restrict__ wq) {
    int idx = blockIdx.x * 256 + threadIdx.x;  // 9*128*64 = 73728
    if (idx < 9 * CO * CI) {
        int tap = idx >> 13;
        int rem = idx & 8191;
        int oc = rem >> 6, ci = rem & 63;
        int kc = ci >> 5, j = ci & 31;
        wq[(((tap * 2 + kc) * CO + oc) << 5) + j] =
            __float2bfloat16(wgt[(oc * CI + ci) * 9 + tap]);
    }
}

// load one input row (all 64 ci for this thread's half) into registers
static __device__ __forceinline__ void loadrow(const float* __restrict__ xb, int r,
                                               int wl, int cg0, float* pf) {
    if ((unsigned)r < (unsigned)H) {
        const float* px = xb + (size_t)r * W + wl;
#pragma unroll
        for (int p = 0; p < 4; ++p) {
            const int cg = cg0 + 2 * p;
#pragma unroll
            for (int j = 0; j < 8; ++j)
                pf[p * 8 + j] = px[(size_t)(cg * 8 + j) * (H * W)];
        }
    } else {
#pragma unroll
        for (int i = 0; i < 32; ++i) pf[i] = 0.0f;
    }
}

// cvt + swizzled ds_write into a row slot; per-thread column partial -> psb
static __device__ __forceinline__ void writerow(__hip_bfloat16* __restrict__ xs,
                                                float* __restrict__ psb, int tid,
                                                int wslot, int cg0, const float* pf) {
    const int wsw = wslot & 7;
    float part = 0.0f;
#pragma unroll
    for (int p = 0; p < 4; ++p) {
        const int cg = cg0 + 2 * p;
        short8 pk;
#pragma unroll
        for (int j = 0; j < 8; ++j) {
            pk[j] = bf16s(pf[p * 8 + j]);
            part += pf[p * 8 + j];
        }
        *(short8*)&xs[wslot * 64 + ((cg ^ wsw) * 8)] = pk;
    }
    psb[tid] = part;
}

__global__ __launch_bounds__(256, 2)
void conv_fused(const float* __restrict__ x,
                const __hip_bfloat16* __restrict__ wq,
                const float* __restrict__ bias,
                float* __restrict__ out) {
    __shared__ __hip_bfloat16 xrow[3][130 * 64];  // 49,920 B rolling rows
    __shared__ float Srow[3][132];                 // rolling per-row col sums
    __shared__ float ps3[132];                     // 3-row-summed cols for h
    __shared__ float psb[256];                     // staging partials

    const int tid = threadIdx.x, bx = blockIdx.x, b = blockIdx.y;
    // XCD-coherent: xcd = bx&7 owns strips [4k,4k+4) = h [16k, 16k+16)
    const int u = ((bx & 7) << 2) | (bx >> 3);
    const int h0 = u * SH;
    const int lane = tid & 63, waveid = tid >> 6;
    const int lo16 = lane & 15, quad = lane >> 4;
    const int m0 = (waveid & 1) * 64, n0 = (waveid >> 1) * 64;
    const int wl = tid & 127, cg0 = tid >> 7, wslot = wl + 1;

    const float* xb = x + (size_t)b * CI * H * W;

    // ---- permanent-zero halo columns (slots 0,129 of all 3 row slots)
    if (tid < 48) {
        const int sl = tid >> 4, col = (tid & 8) ? 129 : 0, uu = tid & 7;
        short8 z = {0, 0, 0, 0, 0, 0, 0, 0};
        *(short8*)&xrow[sl][col * 64 + ((uu ^ (col & 7)) * 8)] = z;
    }
    if (tid == 48) ps3[0] = 0.0f;
    if (tid == 49) ps3[129] = 0.0f;

    // ---- prologue: rows h0-1, h0 (reduced), h0+1 (reduction deferred)
#pragma unroll
    for (int k = 0; k < 2; ++k) {
        const int r = h0 - 1 + k;
        float pf[32];
        loadrow(xb, r, wl, cg0, pf);
        writerow(&xrow[(r + 1) % 3][0], psb, tid, wslot, cg0, pf);
        bar_lgkm();
        if (tid < 128) Srow[(r + 1) % 3][tid + 1] = psb[tid] + psb[tid + 128];
        bar_lgkm();
    }
    {
        float pf[32];
        loadrow(xb, h0 + 1, wl, cg0, pf);
        writerow(&xrow[(h0 + 2) % 3][0], psb, tid, wslot, cg0, pf);
        bar_lgkm();
    }

    // ---- main loop: one output row per step
    for (int t = 0; t < SH; ++t) {
        const int h = h0 + t;

        // T14: issue next-row loads now; they fly under phase1+MFMA
        float pf[32];
        if (t < SH - 1) loadrow(xb, h + 2, wl, cg0, pf);

        // phase1: reduce row h+1 col sums; build 3-row ps3 (regs only dep)
        if (tid < 128) {
            const float v = psb[tid] + psb[tid + 128];
            Srow[(h + 2) % 3][tid + 1] = v;
            ps3[tid + 1] = Srow[h % 3][tid + 1] + Srow[(h + 1) % 3][tid + 1] + v;
        }
        bar_lgkm();

        // MFMA for row h (rows h-1,h,h+1 live in slots (h+kh)%3)
        f32x4 acc[4][4] = {};
        __builtin_amdgcn_s_setprio(1);
#pragma unroll
        for (int kh = 0; kh < 3; ++kh) {
            const __hip_bfloat16* xs = &xrow[(h + kh) % 3][0];
#pragma unroll
            for (int kw = 0; kw < 3; ++kw) {
                const int tap = kh * 3 + kw;
                short8 bq[2][4];
#pragma unroll
                for (int kc = 0; kc < 2; ++kc)
#pragma unroll
                    for (int ni = 0; ni < 4; ++ni)
                        bq[kc][ni] = *(const short8*)(
                            wq + (((tap * 2 + kc) * CO + n0 + ni * 16 + lo16) << 5) + quad * 8);
#pragma unroll
                for (int kc = 0; kc < 2; ++kc) {
                    short8 af[4];
#pragma unroll
                    for (int mi = 0; mi < 4; ++mi) {
                        const int row = m0 + mi * 16 + lo16 + kw;
                        af[mi] = *(const short8*)
                            &xs[row * 64 + (((kc * 4 + quad) ^ (row & 7)) * 8)];
                    }
#pragma unroll
                    for (int mi = 0; mi < 4; ++mi)
#pragma unroll
                        for (int ni = 0; ni < 4; ++ni)
                            acc[mi][ni] = __builtin_amdgcn_mfma_f32_16x16x32_bf16(
                                af[mi], bq[kc][ni], acc[mi][ni], 0, 0, 0);
                }
            }
        }
        __builtin_amdgcn_s_setprio(0);

        // epilogue row h: + 0.1*(h+w)*patch_sum + bias; fire-and-forget stores
#pragma unroll
        for (int mi = 0; mi < 4; ++mi) {
            const int wbase = m0 + mi * 16 + quad * 4;
            float cs[6];
#pragma unroll
            for (int q2 = 0; q2 < 6; ++q2) cs[q2] = ps3[wbase + q2];
            float ps[4], cf[4];
#pragma unroll
            for (int q2 = 0; q2 < 4; ++q2) {
                ps[q2] = cs[q2] + cs[q2 + 1] + cs[q2 + 2];
                cf[q2] = B_COEF * (float)(h + wbase + q2);
            }
#pragma unroll
            for (int ni = 0; ni < 4; ++ni) {
                const int oc = n0 + ni * 16 + lo16;
                const float bv = bias[oc];
                f32x4 v = acc[mi][ni];
#pragma unroll
                for (int q2 = 0; q2 < 4; ++q2) v[q2] = v[q2] + cf[q2] * ps[q2] + bv;
                *(f32x4*)(out + (((size_t)b * CO + oc) * H + h) * W + wbase) = v;
            }
        }
        bar_plain();  // all reads of slot h%3 done; stores keep flying

        // write prefetched row h+2 into the freed slot (h%3)
        if (t < SH - 1) {
            writerow(&xrow[h % 3][0], psb, tid, wslot, cg0, pf);
            bar_lgkm();
        }
    }
}

// ===================== fallback path (R2, needs only 147 KB ws) ============

constexpr int WPAD = 72;

__global__ void prep_w_fb(const float* __restrict__ wgt, __hip_bfloat16* __restrict__ wt) {
    int idx = blockIdx.x * 256 + threadIdx.x;
    if (idx < 9 * CO * CI) {
        int tap = idx / (CO * CI);
        int rem = idx - tap * (CO * CI);
        int oc = rem >> 6, ci = rem & 63;
        wt[idx] = __float2bfloat16(wgt[(oc * CI + ci) * 9 + tap]);
    }
}

__global__ __launch_bounds__(256, 2)
void conv_fb(const float* __restrict__ x, const __hip_bfloat16* __restrict__ wt,
             const float* __restrict__ bias, float* __restrict__ out) {
    __shared__ __hip_bfloat16 xrow[130 * XPAD];
    __shared__ __hip_bfloat16 wlds[CO * WPAD];
    __shared__ float colsum[132];

    const int tid = threadIdx.x;
    const int h = blockIdx.x, b = blockIdx.y;
    const int lane = tid & 63, waveid = tid >> 6;
    const int lo16 = lane & 15, quad = lane >> 4;
    const int m0 = (waveid & 1) * 64, n0 = (waveid >> 1) * 64;

    f32x4 acc[4][4] = {};
    if (tid < 132) colsum[tid] = 0.0f;
    const float* xb = x + (size_t)b * CI * H * W;

    const int w16 = tid & 15, cipl = (tid >> 4) & 3, rest0 = tid >> 6;

    for (int kh = 0; kh < 3; ++kh) {
        const int gh = h - 1 + kh;
        __syncthreads();
        for (int it = 0; it < 18; ++it) {
            int rest = rest0 + it * 4;
            int whi = rest % 9, ciph = rest / 9;
            int w = whi * 16 + w16;
            int ci0 = (ciph * 4 + cipl) * 2;
            int gw = w - 1;
            float x0 = 0.0f, x1 = 0.0f;
            if (w < 130 && gw >= 0 && gw < W && gh >= 0 && gh < H) {
                const float* p = xb + (size_t)ci0 * (H * W) + gh * W + gw;
                x0 = p[0];
                x1 = p[H * W];
            }
            if (w < 130) {
                __hip_bfloat162 pk;
                pk.x = __float2bfloat16(x0);
                pk.y = __float2bfloat16(x1);
                *(__hip_bfloat162*)&xrow[w * XPAD + ci0] = pk;
            }
            float cs = x0 + x1;
            cs += __shfl_xor(cs, 16);
            cs += __shfl_xor(cs, 32);
            if (quad == 0 && w < 130) atomicAdd(&colsum[w], cs);
        }
        for (int kw = 0; kw < 3; ++kw) {
            __syncthreads();
            {
                const __hip_bfloat16* wtap = wt + (kh * 3 + kw) * (CO * CI);
#pragma unroll
                for (int it = 0; it < 4; ++it) {
                    int j = tid + it * 256;
                    int oc = j >> 3, ch = (j & 7) * 8;
                    short8 v = *(const short8*)(wtap + oc * CI + ch);
                    *(short8*)&wlds[oc * WPAD + ch] = v;
                }
            }
            __syncthreads();
#pragma unroll
            for (int kc = 0; kc < 2; ++kc) {
                const int krow = kc * 32 + quad * 8;
                short8 af[4], bf[4];
#pragma unroll
                for (int mi = 0; mi < 4; ++mi)
                    af[mi] = *(const short8*)&xrow[(m0 + mi * 16 + lo16 + kw) * XPAD + krow];
#pragma unroll
                for (int ni = 0; ni < 4; ++ni)
                    bf[ni] = *(const short8*)&wlds[(n0 + ni * 16 + lo16) * WPAD + krow];
#pragma unroll
                for (int mi = 0; mi < 4; ++mi)
#pragma unroll
                    for (int ni = 0; ni < 4; ++ni)
                        acc[mi][ni] = __builtin_amdgcn_mfma_f32_16x16x32_bf16(
                            af[mi], bf[ni], acc[mi][ni], 0, 0, 0);
            }
        }
    }
    __syncthreads();
#pragma unroll
    for (int mi = 0; mi < 4; ++mi) {
        const int wbase = m0 + mi * 16 + quad * 4;
        float cs[6];
#pragma unroll
        for (int r = 0; r < 6; ++r) cs[r] = colsum[wbase + r];
        float ps[4], cf[4];
#pragma unroll
        for (int r = 0; r < 4; ++r) {
            ps[r] = cs[r] + cs[r + 1] + cs[r + 2];
            cf[r] = B_COEF * (float)(h + wbase + r);
        }
#pragma unroll
        for (int ni = 0; ni < 4; ++ni) {
            const int oc = n0 + ni * 16 + lo16;
            const float bv = bias[oc];
            f32x4 v = acc[mi][ni];
#pragma unroll
            for (int r = 0; r < 4; ++r) v[r] = v[r] + cf[r] * ps[r] + bv;
            *(f32x4*)(out + (((size_t)b * CO + oc) * H + h) * W + wbase) = v;
        }
    }
}

// ===========================================================================

extern "C" void kernel_launch(void* const* d_in, const int* in_sizes, int n_in,
                              void* d_out, int out_size, void* d_ws, size_t ws_size,
                              hipStream_t stream) {
    const float* x    = (const float*)d_in[0];
    const float* wgt  = (const float*)d_in[1];
    const float* bias = (const float*)d_in[2];
    float* out = (float*)d_out;

    const size_t WQ_BYTES = (size_t)9 * 2 * CO * 32 * 2;  // 147,456

    if (ws_size >= WQ_BYTES) {
        __hip_bfloat16* wq = (__hip_bfloat16*)d_ws;
        prep_wq<<<dim3(288), dim3(256), 0, stream>>>(wgt, wq);
        conv_fused<<<dim3(H / SH, 16), dim3(256), 0, stream>>>(x, wq, bias, out);
    } else {
        __hip_bfloat16* wt = (__hip_bfloat16*)d_ws;  // 147,456 B
        prep_w_fb<<<dim3(288), dim3(256), 0, stream>>>(wgt, wt);
        conv_fb<<<dim3(H, 16), dim3(256), 0, stream>>>(x, wt, bias, out);
    }
}

// Round 6
// 234.390 us; speedup vs baseline: 1.1014x; 1.1014x over previous
//
#include <hip/hip_runtime.h>
#include <hip/hip_bf16.h>

// PatchConv2d: out[b,o,h,w] = conv3x3(x,kernel) + 0.1*(h+w)*patch_sum[b,h,w] + bias[o]
// x:(16,64,128,128) f32, kernel:(128,64,3,3) f32, bias:(128,) f32 -> out(16,128,128,128) f32
//
// R9: R8's rolling pipeline, de-spilled. 512-thread blocks (8 waves), each
//     wave 64w x 32oc -> acc[4][2]=32 VGPR; per-thread prefetch pf[16].
//     4-slot LDS row ring (slot(row)=(row+1)&3): prefetched row is written
//     to the FREE slot BEFORE the MFMA phase, so nothing is held across MFMA
//     except the 16 in-flight loads. Two lgkm-only barriers per step, no
//     vmcnt drain (stores + prefetch fly across). 2 blocks/CU (71 KB LDS),
//     grid 512 = exactly 2/CU, zero tail. XCD-coherent h-strips.

typedef __attribute__((ext_vector_type(8))) short short8;
typedef __attribute__((ext_vector_type(4))) float f32x4;

#define B_COEF 0.1f
constexpr int CI = 64, CO = 128, H = 128, W = 128;
constexpr int SH = 4;     // output rows per block
constexpr int XPAD = 72;  // fallback-path LDS stride

static __device__ inline short bf16s(float v) {
    __hip_bfloat16 b = __float2bfloat16(v);
    return *reinterpret_cast<short*>(&b);
}

// barrier that does NOT drain vmcnt: ds ops flushed, global loads/stores fly
static __device__ inline void bar_lgkm() {
    asm volatile("s_waitcnt lgkmcnt(0)" ::: "memory");
    __builtin_amdgcn_s_barrier();
    asm volatile("" ::: "memory");
}

// ============================ fast path ====================================

// kernel f32 [oc][ci][3][3] -> bf16 wq[tap][kc][oc][32] (ci = kc*32+j)
__global__ void prep_wq(const float* __restrict__ wgt, __hip_bfloat16* __restrict__ wq) {
    int idx = blockIdx.x * 256 + threadIdx.x;  // 9*128*64 = 73728
    if (idx < 9 * CO * CI) {
        int tap = idx >> 13;
        int rem = idx & 8191;
        int oc = rem >> 6, ci = rem & 63;
        int kc = ci >> 5, j = ci & 31;
        wq[(((tap * 2 + kc) * CO + oc) << 5) + j] =
            __float2bfloat16(wgt[(oc * CI + ci) * 9 + tap]);
    }
}

// load one input row: this thread's 2 ci-units (16 f32), coalesced dwords
static __device__ __forceinline__ void loadrow(const float* __restrict__ xb, int r,
                                               int wl, int u0, float* pf) {
    if ((unsigned)r < (unsigned)H) {
        const float* px = xb + (size_t)r * W + wl;
#pragma unroll
        for (int uu = 0; uu < 2; ++uu)
#pragma unroll
            for (int j = 0; j < 8; ++j)
                pf[uu * 8 + j] = px[(size_t)((u0 + uu) * 8 + j) * (H * W)];
    } else {
#pragma unroll
        for (int i = 0; i < 16; ++i) pf[i] = 0.0f;
    }
}

// cvt + swizzled ds_write into a row slot; per-thread column partial -> psb
static __device__ __forceinline__ void writerow(__hip_bfloat16* __restrict__ xs,
                                                float* __restrict__ psb, int tid,
                                                int wslot, int u0, const float* pf) {
    const int wsw = wslot & 7;
    float part = 0.0f;
#pragma unroll
    for (int uu = 0; uu < 2; ++uu) {
        short8 pk;
#pragma unroll
        for (int j = 0; j < 8; ++j) {
            pk[j] = bf16s(pf[uu * 8 + j]);
            part += pf[uu * 8 + j];
        }
        *(short8*)&xs[wslot * 64 + (((u0 + uu) ^ wsw) * 8)] = pk;
    }
    psb[tid] = part;
}

__global__ __launch_bounds__(512, 2)
void conv_fused(const float* __restrict__ x,
                const __hip_bfloat16* __restrict__ wq,
                const float* __restrict__ bias,
                float* __restrict__ out) {
    __shared__ __hip_bfloat16 xrow[4][130 * 64];  // 66,560 B row ring
    __shared__ float Srow[4][132];                 // per-slot col sums
    __shared__ float ps3[132];                     // 3-row-summed cols for h
    __shared__ float psb[512];                     // staging partials

    const int tid = threadIdx.x, bx = blockIdx.x, b = blockIdx.y;
    // XCD-coherent: xcd = bx&7 owns strips -> h in [16*xcd, 16*xcd+16)
    const int u = ((bx & 7) << 2) | (bx >> 3);
    const int h0 = u * SH;
    const int lane = tid & 63, waveid = tid >> 6;
    const int lo16 = lane & 15, quad = lane >> 4;
    const int m0 = (waveid & 1) * 64, n0 = (waveid >> 1) * 32;
    const int wl = tid & 127, u0 = (tid >> 7) * 2, wslot = wl + 1;

    const float* xb = x + (size_t)b * CI * H * W;

    // ---- permanent-zero halo columns (slots 0,129 of all 4 ring slots)
    if (tid < 64) {
        const int sl = tid >> 4, col = (tid & 8) ? 129 : 0, uu = tid & 7;
        short8 z = {0, 0, 0, 0, 0, 0, 0, 0};
        *(short8*)&xrow[sl][col * 64 + ((uu ^ (col & 7)) * 8)] = z;
    }
    if (tid == 64) ps3[0] = 0.0f;
    if (tid == 65) ps3[129] = 0.0f;

    // ---- prologue: batch-load rows h0-1..h0+2 (64 loads in flight),
    //      then write+reduce rows h0-1..h0+1; keep row h0+2 in pfA.
    float pr0[16], pr1[16], pr2[16], pfA[16], pfB[16];
    loadrow(xb, h0 - 1, wl, u0, pr0);
    loadrow(xb, h0,     wl, u0, pr1);
    loadrow(xb, h0 + 1, wl, u0, pr2);
    loadrow(xb, h0 + 2, wl, u0, pfA);
#pragma unroll
    for (int k = 0; k < 3; ++k) {
        const int r = h0 - 1 + k;
        const float* pk = (k == 0) ? pr0 : (k == 1) ? pr1 : pr2;
        writerow(&xrow[(r + 1) & 3][0], psb, tid, wslot, u0, pk);
        bar_lgkm();
        if (tid < 128)
            Srow[(r + 1) & 3][tid + 1] =
                psb[tid] + psb[tid + 128] + psb[tid + 256] + psb[tid + 384];
        bar_lgkm();
    }

    // ---- main loop: one output row per step (fully unrolled, ping-pong pf)
#pragma unroll
    for (int t = 0; t < SH; ++t) {
        const int h = h0 + t;

        // issue next prefetch (flies under this step's MFMA + epilogue)
        if (t == 0) loadrow(xb, h0 + 3, wl, u0, pfB);
        if (t == 1) loadrow(xb, h0 + 4, wl, u0, pfA);

        // ps3 for row h from stable Srow slots (rows h-1,h,h+1)
        if (tid < 128)
            ps3[tid + 1] = Srow[h & 3][tid + 1] + Srow[(h + 1) & 3][tid + 1] +
                           Srow[(h + 2) & 3][tid + 1];

        // write row h+2 (loaded last step) into the FREE slot (h+3)&3
        if (t < 3)
            writerow(&xrow[(h + 3) & 3][0], psb, tid, wslot, u0,
                     (t & 1) ? pfB : pfA);
        bar_lgkm();
        if (t < 3 && tid < 128)
            Srow[(h + 3) & 3][tid + 1] =
                psb[tid] + psb[tid + 128] + psb[tid + 256] + psb[tid + 384];

        // ---- MFMA row h (ring slots (h..h+2)&3; write slot not among them)
        f32x4 acc[4][2] = {};
        __builtin_amdgcn_s_setprio(1);
#pragma unroll
        for (int kh = 0; kh < 3; ++kh) {
            const __hip_bfloat16* xs = &xrow[(h + kh) & 3][0];
#pragma unroll
            for (int kw = 0; kw < 3; ++kw) {
                const int tap = kh * 3 + kw;
                short8 bq[2][2];
#pragma unroll
                for (int kc = 0; kc < 2; ++kc)
#pragma unroll
                    for (int ni = 0; ni < 2; ++ni)
                        bq[kc][ni] = *(const short8*)(
                            wq + (((tap * 2 + kc) * CO + n0 + ni * 16 + lo16) << 5) + quad * 8);
#pragma unroll
                for (int kc = 0; kc < 2; ++kc) {
                    short8 af[4];
#pragma unroll
                    for (int mi = 0; mi < 4; ++mi) {
                        const int row = m0 + mi * 16 + lo16 + kw;
                        af[mi] = *(const short8*)
                            &xs[row * 64 + (((kc * 4 + quad) ^ (row & 7)) * 8)];
                    }
#pragma unroll
                    for (int mi = 0; mi < 4; ++mi)
#pragma unroll
                        for (int ni = 0; ni < 2; ++ni)
                            acc[mi][ni] = __builtin_amdgcn_mfma_f32_16x16x32_bf16(
                                af[mi], bq[kc][ni], acc[mi][ni], 0, 0, 0);
                }
            }
        }
        __builtin_amdgcn_s_setprio(0);

        // ---- epilogue row h: + 0.1*(h+w)*patch_sum + bias; stores fly
#pragma unroll
        for (int mi = 0; mi < 4; ++mi) {
            const int wbase = m0 + mi * 16 + quad * 4;
            float cs[6];
#pragma unroll
            for (int q2 = 0; q2 < 6; ++q2) cs[q2] = ps3[wbase + q2];
            float ps[4], cf[4];
#pragma unroll
            for (int q2 = 0; q2 < 4; ++q2) {
                ps[q2] = cs[q2] + cs[q2 + 1] + cs[q2 + 2];
                cf[q2] = B_COEF * (float)(h + wbase + q2);
            }
#pragma unroll
            for (int ni = 0; ni < 2; ++ni) {
                const int oc = n0 + ni * 16 + lo16;
                const float bv = bias[oc];
                f32x4 v = acc[mi][ni];
#pragma unroll
                for (int q2 = 0; q2 < 4; ++q2) v[q2] = v[q2] + cf[q2] * ps[q2] + bv;
                *(f32x4*)(out + (((size_t)b * CO + oc) * H + h) * W + wbase) = v;
            }
        }
        if (t < SH - 1) bar_lgkm();  // end of step: Srow visible, slot freed
    }
}

// ===================== fallback path (R2, needs only 147 KB ws) ============

constexpr int WPAD = 72;

__global__ void prep_w_fb(const float* __restrict__ wgt, __hip_bfloat16* __restrict__ wt) {
    int idx = blockIdx.x * 256 + threadIdx.x;
    if (idx < 9 * CO * CI) {
        int tap = idx / (CO * CI);
        int rem = idx - tap * (CO * CI);
        int oc = rem >> 6, ci = rem & 63;
        wt[idx] = __float2bfloat16(wgt[(oc * CI + ci) * 9 + tap]);
    }
}

__global__ __launch_bounds__(256, 2)
void conv_fb(const float* __restrict__ x, const __hip_bfloat16* __restrict__ wt,
             const float* __restrict__ bias, float* __restrict__ out) {
    __shared__ __hip_bfloat16 xrow[130 * XPAD];
    __shared__ __hip_bfloat16 wlds[CO * WPAD];
    __shared__ float colsum[132];

    const int tid = threadIdx.x;
    const int h = blockIdx.x, b = blockIdx.y;
    const int lane = tid & 63, waveid = tid >> 6;
    const int lo16 = lane & 15, quad = lane >> 4;
    const int m0 = (waveid & 1) * 64, n0 = (waveid >> 1) * 64;

    f32x4 acc[4][4] = {};
    if (tid < 132) colsum[tid] = 0.0f;
    const float* xb = x + (size_t)b * CI * H * W;

    const int w16 = tid & 15, cipl = (tid >> 4) & 3, rest0 = tid >> 6;

    for (int kh = 0; kh < 3; ++kh) {
        const int gh = h - 1 + kh;
        __syncthreads();
        for (int it = 0; it < 18; ++it) {
            int rest = rest0 + it * 4;
            int whi = rest % 9, ciph = rest / 9;
            int w = whi * 16 + w16;
            int ci0 = (ciph * 4 + cipl) * 2;
            int gw = w - 1;
            float x0 = 0.0f, x1 = 0.0f;
            if (w < 130 && gw >= 0 && gw < W && gh >= 0 && gh < H) {
                const float* p = xb + (size_t)ci0 * (H * W) + gh * W + gw;
                x0 = p[0];
                x1 = p[H * W];
            }
            if (w < 130) {
                __hip_bfloat162 pk;
                pk.x = __float2bfloat16(x0);
                pk.y = __float2bfloat16(x1);
                *(__hip_bfloat162*)&xrow[w * XPAD + ci0] = pk;
            }
            float cs = x0 + x1;
            cs += __shfl_xor(cs, 16);
            cs += __shfl_xor(cs, 32);
            if (quad == 0 && w < 130) atomicAdd(&colsum[w], cs);
        }
        for (int kw = 0; kw < 3; ++kw) {
            __syncthreads();
            {
                const __hip_bfloat16* wtap = wt + (kh * 3 + kw) * (CO * CI);
#pragma unroll
                for (int it = 0; it < 4; ++it) {
                    int j = tid + it * 256;
                    int oc = j >> 3, ch = (j & 7) * 8;
                    short8 v = *(const short8*)(wtap + oc * CI + ch);
                    *(short8*)&wlds[oc * WPAD + ch] = v;
                }
            }
            __syncthreads();
#pragma unroll
            for (int kc = 0; kc < 2; ++kc) {
                const int krow = kc * 32 + quad * 8;
                short8 af[4], bf[4];
#pragma unroll
                for (int mi = 0; mi < 4; ++mi)
                    af[mi] = *(const short8*)&xrow[(m0 + mi * 16 + lo16 + kw) * XPAD + krow];
#pragma unroll
                for (int ni = 0; ni < 4; ++ni)
                    bf[ni] = *(const short8*)&wlds[(n0 + ni * 16 + lo16) * WPAD + krow];
#pragma unroll
                for (int mi = 0; mi < 4; ++mi)
#pragma unroll
                    for (int ni = 0; ni < 4; ++ni)
                        acc[mi][ni] = __builtin_amdgcn_mfma_f32_16x16x32_bf16(
                            af[mi], bf[ni], acc[mi][ni], 0, 0, 0);
            }
        }
    }
    __syncthreads();
#pragma unroll
    for (int mi = 0; mi < 4; ++mi) {
        const int wbase = m0 + mi * 16 + quad * 4;
        float cs[6];
#pragma unroll
        for (int r = 0; r < 6; ++r) cs[r] = colsum[wbase + r];
        float ps[4], cf[4];
#pragma unroll
        for (int r = 0; r < 4; ++r) {
            ps[r] = cs[r] + cs[r + 1] + cs[r + 2];
            cf[r] = B_COEF * (float)(h + wbase + r);
        }
#pragma unroll
        for (int ni = 0; ni < 4; ++ni) {
            const int oc = n0 + ni * 16 + lo16;
            const float bv = bias[oc];
            f32x4 v = acc[mi][ni];
#pragma unroll
            for (int r = 0; r < 4; ++r) v[r] = v[r] + cf[r] * ps[r] + bv;
            *(f32x4*)(out + (((size_t)b * CO + oc) * H + h) * W + wbase) = v;
        }
    }
}

// ===========================================================================

extern "C" void kernel_launch(void* const* d_in, const int* in_sizes, int n_in,
                              void* d_out, int out_size, void* d_ws, size_t ws_size,
                              hipStream_t stream) {
    const float* x    = (const float*)d_in[0];
    const float* wgt  = (const float*)d_in[1];
    const float* bias = (const float*)d_in[2];
    float* out = (float*)d_out;

    const size_t WQ_BYTES = (size_t)9 * 2 * CO * 32 * 2;  // 147,456

    if (ws_size >= WQ_BYTES) {
        __hip_bfloat16* wq = (__hip_bfloat16*)d_ws;
        prep_wq<<<dim3(288), dim3(256), 0, stream>>>(wgt, wq);
        conv_fused<<<dim3(H / SH, 16), dim3(512), 0, stream>>>(x, wq, bias, out);
    } else {
        __hip_bfloat16* wt = (__hip_bfloat16*)d_ws;  // 147,456 B
        prep_w_fb<<<dim3(288), dim3(256), 0, stream>>>(wgt, wt);
        conv_fb<<<dim3(H, 16), dim3(256), 0, stream>>>(x, wt, bias, out);
    }
}